// Round 6
// baseline (1007.932 us; speedup 1.0000x reference)
//
#include <hip/hip_runtime.h>
#include <cmath>

// ---- problem constants ----
constexpr int DM     = 768;     // d_model
constexpr int DI     = 1536;    // d_inner
constexpr int DI2    = 3072;    // 2*d_inner
constexpr int DSTATE = 16;
constexpr int DTRANK = 48;
constexpr int NDBC   = 80;      // dt_rank + 2*d_state
constexpr int BB     = 2;
constexpr int LL     = 1024;
constexpr int NT     = BB * LL; // 2048 tokens
constexpr int NVOCAB = 32000;
constexpr float EPSF = 1e-5f;
constexpr float LOG2E = 1.4426950408889634f;

// chunked scan parameters
constexpr int NC = 64;          // chunks along L
constexpr int CL = LL / NC;     // 16 steps per chunk

typedef unsigned short ushort_t;
typedef __bf16 bf16x8 __attribute__((ext_vector_type(8)));
typedef float  f32x4  __attribute__((ext_vector_type(4)));

__device__ inline ushort_t f2bf(float x) {
    unsigned int u = __builtin_bit_cast(unsigned int, x);
    unsigned int r = (u + 0x7FFFu + ((u >> 16) & 1u)) >> 16;
    return (ushort_t)r;
}

// ------------------- fp32 -> bf16 bulk convert (RNE) -------------------
__global__ __launch_bounds__(256) void f2b_kernel(const float* __restrict__ in,
                                                  ushort_t* __restrict__ out, int n4) {
    int i = blockIdx.x * blockDim.x + threadIdx.x;
    if (i >= n4) return;
    float4 v = ((const float4*)in)[i];
    ushort4 o;
    o.x = f2bf(v.x); o.y = f2bf(v.y); o.z = f2bf(v.z); o.w = f2bf(v.w);
    ((ushort4*)out)[i] = o;
}

// ------------------- embedding gather -------------------
__global__ void embed_kernel(const int* __restrict__ x, const float* __restrict__ W,
                             float* __restrict__ h) {
    int t = blockIdx.x;
    int row = x[t];
    const float4* src = (const float4*)(W + (size_t)row * DM);
    float4* dst = (float4*)(h + (size_t)t * DM);
    for (int i = threadIdx.x; i < DM / 4; i += blockDim.x) dst[i] = src[i];
}

// ------------------- per-token RMSNorm, bf16 output -------------------
// optional: zero-fills zfill (NT x DI2) for split-K in_proj accumulation
__global__ __launch_bounds__(256) void rmsnorm_kernel(const float* __restrict__ x,
                                                      const float* __restrict__ w,
                                                      ushort_t* __restrict__ o,
                                                      float* __restrict__ zfill) {
    int t = blockIdx.x;
    if (zfill) {
        float4* zr = (float4*)(zfill + (size_t)t * DI2);
        #pragma unroll
        for (int i = 0; i < 3; ++i) zr[threadIdx.x + i * 256] = make_float4(0.f, 0.f, 0.f, 0.f);
    }
    const float* xr = x + (size_t)t * DM;
    float s = 0.f;
    for (int i = threadIdx.x; i < DM; i += 256) { float v = xr[i]; s += v * v; }
    #pragma unroll
    for (int off = 32; off >= 1; off >>= 1) s += __shfl_down(s, off, 64);
    __shared__ float wsum[4];
    if ((threadIdx.x & 63) == 0) wsum[threadIdx.x >> 6] = s;
    __syncthreads();
    float tot = wsum[0] + wsum[1] + wsum[2] + wsum[3];
    float r = rsqrtf(tot / DM + EPSF);
    ushort_t* orow = o + (size_t)t * DM;
    for (int i = threadIdx.x; i < DM; i += 256) orow[i] = f2bf(xr[i] * r * w[i]);
}

// ------------------- bf16 MFMA GEMM: C[m,n] = sum_k A[m,k]*W[n,k] -------------------
// 128x128 tile, BK=32, 4 waves (2x2), 4x4 16x16x32 MFMA tiles per wave.
// + T1 bijective XCD swizzle (W-panel L2 locality)
// + T2 both-sides LDS XOR swizzle (bank-conflict-free, verified 0 conflicts r2)
// + depth-2 COUNTED pipeline at 32 KB LDS (5 blocks/CU — occupancy beats depth, r3):
//   vmcnt(4) -> barrier(A) publish buf[s] -> ds_read 8 frags -> lgkmcnt(0)
//   -> barrier(B) -> stage(s+2) overwriting buf[s] -> MFMA.
// + T5 setprio around MFMA cluster.
// + split-K via gridDim.z>1: each z-slice does K/nz, epilogue atomicAdd into C
//   (C must hold the base value, e.g. residual; bias/resid args ignored then).
// Requires M%128==0, N%128==0, (K/nz)%32==0, (K/nz)/32>=2.
__device__ inline void gl_lds16(const void* g, void* l) {
    auto gp = (const __attribute__((address_space(1))) void*)(unsigned long long)(uintptr_t)g;
    auto lp = (__attribute__((address_space(3))) void*)(unsigned int)(uintptr_t)l;
    __builtin_amdgcn_global_load_lds(gp, lp, 16, 0, 0);
}

__global__ __launch_bounds__(256) void bgemm_bt(const ushort_t* __restrict__ A, int lda,
                                                const ushort_t* __restrict__ W, int ldw,
                                                float* __restrict__ C, int ldc,
                                                int K,
                                                const float* __restrict__ bias,
                                                const float* __restrict__ resid) {
    __shared__ ushort_t As[2][128 * 32];
    __shared__ ushort_t Bs[2][128 * 32];

    // T1: bijective XCD swizzle (m204): contiguous wg chunks per XCD (x,y only)
    const int GX  = gridDim.x;
    const int nwg = GX * gridDim.y;
    int orig = blockIdx.y * GX + blockIdx.x;
    int q = nwg >> 3, r = nwg & 7, xcd = orig & 7, lq = orig >> 3;
    int wg = (xcd < r ? xcd * (q + 1) : r * (q + 1) + (xcd - r) * q) + lq;
    const int m0 = (wg % GX) * 128;
    const int n0 = (wg / GX) * 128;

    // split-K slice
    const int nz   = gridDim.z;
    const int Kc   = K / nz;
    const int kbeg = blockIdx.z * Kc;

    const int wave = threadIdx.x >> 6;
    const int lane = threadIdx.x & 63;
    const int lrow = lane >> 2;          // 0..15 (staging row within 16-row group)

    f32x4 acc[4][4] = {};

    const ushort_t* Ab = A + (size_t)m0 * lda + kbeg;
    const ushort_t* Wb = W + (size_t)n0 * ldw + kbeg;
    const int wm = (wave >> 1) * 64;
    const int wn = (wave & 1) * 64;

    // staging: lane writes LDS[row][lane&3] (linear dest), loads global chunk
    // (lane&3)^swz(row) so that LDS[row][p] holds global chunk p^swz(row).
    auto stage = [&](int buf, int k0) {
        #pragma unroll
        for (int rr = 0; rr < 2; ++rr) {
            const int rowbase = rr * 64 + wave * 16;
            const int row = rowbase + lrow;
            const int csw = (((lane & 3) ^ ((row >> 1) & 3)) << 3);   // elems
            gl_lds16(Ab + (size_t)row * lda + k0 + csw, (char*)As[buf] + rowbase * 64);
            gl_lds16(Wb + (size_t)row * ldw + k0 + csw, (char*)Bs[buf] + rowbase * 64);
        }
    };

    const int S = Kc >> 5;               // K-steps (>=2 for all our shapes)
    stage(0, 0);
    stage(1, 32);

    const int rsw = ((lane >> 1) & 3);   // swz(row) for read: row&15 == lane&15
    for (int s = 0; s < S; ++s) {
        // own loads of buf[s&1] retired; (s+1)'s 4 loads may remain in flight
        if (s < S - 1) asm volatile("s_waitcnt vmcnt(4)" ::: "memory");
        else           asm volatile("s_waitcnt vmcnt(0)" ::: "memory");
        __builtin_amdgcn_s_barrier();            // (A) publish buf[s&1]

        const int cur = s & 1;
        bf16x8 af[4], bfr[4];
        const int rchunk = (((lane >> 4) ^ rsw) << 4);   // bytes
        #pragma unroll
        for (int i = 0; i < 4; ++i) {
            af[i]  = *(const bf16x8*)((char*)As[cur] + (wm + i * 16 + (lane & 15)) * 64 + rchunk);
            bfr[i] = *(const bf16x8*)((char*)Bs[cur] + (wn + i * 16 + (lane & 15)) * 64 + rchunk);
        }
        asm volatile("s_waitcnt lgkmcnt(0)" ::: "memory");  // my reads in regs
        __builtin_amdgcn_sched_barrier(0);
        __builtin_amdgcn_s_barrier();            // (B) all waves' reads of buf[cur] done
        if (s + 2 < S) stage(cur, (s + 2) << 5); // overwrite buf[cur] with tile s+2

        __builtin_amdgcn_s_setprio(1);
        #pragma unroll
        for (int i = 0; i < 4; ++i)
            #pragma unroll
            for (int j = 0; j < 4; ++j)
                acc[i][j] = __builtin_amdgcn_mfma_f32_16x16x32_bf16(af[i], bfr[j], acc[i][j], 0, 0, 0);
        __builtin_amdgcn_s_setprio(0);
    }

    // epilogue: C/D layout col=lane&15, row=(lane>>4)*4+reg
    const int cn = lane & 15;
    const int cr = (lane >> 4) * 4;
    #pragma unroll
    for (int i = 0; i < 4; ++i) {
        #pragma unroll
        for (int j = 0; j < 4; ++j) {
            const int col = n0 + wn + j * 16 + cn;
            const float bv = (nz == 1 && bias) ? bias[col] : 0.f;
            #pragma unroll
            for (int rr = 0; rr < 4; ++rr) {
                const int row = m0 + wm + i * 16 + cr + rr;
                const size_t idx = (size_t)row * ldc + col;
                if (nz > 1) {
                    atomicAdd(&C[idx], acc[i][j][rr]);
                } else {
                    float v = acc[i][j][rr] + bv;
                    if (resid) v += resid[idx];
                    C[idx] = v;
                }
            }
        }
    }
}

// ------------------- fp32 tiled GEMM (small N / small K cases) -------------------
// gridDim.z > 1 => split-K: each z-slice handles K/gridDim.z, accumulates into C
// via atomicAdd (C must be pre-zeroed; bias/resid/act must be off on that path).
constexpr int BM = 64, BN = 64, BK = 16;
__global__ __launch_bounds__(256) void sgemm_bt(const float* __restrict__ A, int lda,
                                                const float* __restrict__ W, int ldw,
                                                float* __restrict__ C, int ldc,
                                                int M, int N, int K,
                                                const float* __restrict__ bias,
                                                const float* __restrict__ resid,
                                                int act) {
    __shared__ float As[BK][BM];
    __shared__ float Ws[BK][BN];
    const int m0 = blockIdx.x * BM;
    const int n0 = blockIdx.y * BN;
    const int nz = gridDim.z;
    const int Kc = K / nz;
    const int kbeg = blockIdx.z * Kc;
    const int kend = kbeg + Kc;
    const int tid = threadIdx.x;
    const int tn = tid & 15, tm = tid >> 4;
    const int lr = tid >> 2;
    const int lk = (tid & 3) * 4;

    float acc[4][4] = {};

    for (int k0 = kbeg; k0 < kend; k0 += BK) {
        {
            float4 v = *(const float4*)(A + (size_t)(m0 + lr) * lda + k0 + lk);
            As[lk + 0][lr] = v.x; As[lk + 1][lr] = v.y;
            As[lk + 2][lr] = v.z; As[lk + 3][lr] = v.w;
            int n = n0 + lr;
            float4 u = make_float4(0.f, 0.f, 0.f, 0.f);
            if (n < N) u = *(const float4*)(W + (size_t)n * ldw + k0 + lk);
            Ws[lk + 0][lr] = u.x; Ws[lk + 1][lr] = u.y;
            Ws[lk + 2][lr] = u.z; Ws[lk + 3][lr] = u.w;
        }
        __syncthreads();
        #pragma unroll
        for (int kk = 0; kk < BK; ++kk) {
            float4 a = *(const float4*)&As[kk][tm * 4];
            float4 w = *(const float4*)&Ws[kk][tn * 4];
            acc[0][0] += a.x * w.x; acc[0][1] += a.x * w.y; acc[0][2] += a.x * w.z; acc[0][3] += a.x * w.w;
            acc[1][0] += a.y * w.x; acc[1][1] += a.y * w.y; acc[1][2] += a.y * w.z; acc[1][3] += a.y * w.w;
            acc[2][0] += a.z * w.x; acc[2][1] += a.z * w.y; acc[2][2] += a.z * w.z; acc[2][3] += a.z * w.w;
            acc[3][0] += a.w * w.x; acc[3][1] += a.w * w.y; acc[3][2] += a.w * w.z; acc[3][3] += a.w * w.w;
        }
        __syncthreads();
    }

    #pragma unroll
    for (int i = 0; i < 4; ++i) {
        int m = m0 + tm * 4 + i;
        #pragma unroll
        for (int j = 0; j < 4; ++j) {
            int n = n0 + tn * 4 + j;
            if (n < N) {
                const size_t idx = (size_t)m * ldc + n;
                float v = acc[i][j];
                if (nz > 1) {
                    atomicAdd(&C[idx], v);
                } else {
                    if (bias)  v += bias[n];
                    if (resid) v += resid[idx];
                    if (act == 1) v = (v > 20.f) ? v : log1pf(expf(v));
                    C[idx] = v;
                }
            }
        }
    }
}

// ------------------- causal depthwise conv (k=4) + bias + silu -------------------
// also zero-fills dbc (split-K x_proj accumulates into it afterwards)
__global__ void conv_silu_kernel(const float* __restrict__ xz, const float* __restrict__ cw,
                                 const float* __restrict__ cb, float* __restrict__ xa,
                                 float* __restrict__ dbc0) {
    int idx = blockIdx.x * blockDim.x + threadIdx.x;
    if (idx < NT * NDBC) dbc0[idx] = 0.f;
    if (idx >= NT * DI) return;
    int e = idx % DI;
    int t = idx / DI;
    int l = t & (LL - 1);
    float acc = cb[e];
    #pragma unroll
    for (int k = 0; k < 4; ++k) {
        int ll = l - 3 + k;
        if (ll >= 0) acc += cw[e * 4 + k] * xz[(size_t)(t - 3 + k) * DI2 + e];
    }
    xa[idx] = acc / (1.f + expf(-acc));   // silu
}

// ------------------- chunked selective scan -------------------
// Recurrence h_t = dA_t*h_t-1 + dBx_t is linear, so over a chunk:
//   h_end = P * h_in + h_local,  P = exp2(aen * sum(delta))
// Phase 1 (carry): per-(b,chunk,e) thread, 16 states in regs, h_in=0
//                  -> Hc[16] (local sums) + Ds (sum of delta; P recomputed later)
// Phase 2 (compose): serial over chunks per (b,e,n); Hc[c] <- h_in for chunk c
// Phase 3 (apply): re-run chunk scan seeded with h_in; y = sum_n h*C, fuse
//                  D-skip + z-silu.

__global__ __launch_bounds__(256) void scan_carry(const float* __restrict__ delta,
                                                  const float* __restrict__ xa,
                                                  const float* __restrict__ dbc,
                                                  const float* __restrict__ A_log,
                                                  float* __restrict__ Ds,
                                                  float* __restrict__ Hc) {
    const int e = blockIdx.x * 256 + threadIdx.x;
    const int c = blockIdx.y;
    const int b = blockIdx.z;
    float aen[DSTATE], h[DSTATE];
    #pragma unroll
    for (int n = 0; n < DSTATE; ++n) {
        aen[n] = -expf(A_log[e * DSTATE + n]) * LOG2E;   // pre-scale for exp2
        h[n] = 0.f;
    }
    float dsum = 0.f;
    const int t0 = b * LL + c * CL;
    const float* dp = delta + (size_t)t0 * DI + e;
    const float* xp = xa    + (size_t)t0 * DI + e;
    const float* bp = dbc   + (size_t)t0 * NDBC + DTRANK;   // wave-uniform rows
    for (int l = 0; l < CL; ++l) {
        float d  = dp[(size_t)l * DI];
        float xv = xp[(size_t)l * DI];
        const float* br = bp + (size_t)l * NDBC;
        dsum += d;
        float dxv = d * xv;
        #pragma unroll
        for (int n = 0; n < DSTATE; ++n) {
            float dA = exp2f(d * aen[n]);
            h[n] = dA * h[n] + dxv * br[n];
        }
    }
    const size_t cbase = ((size_t)(b * NC + c) * DI + e) * DSTATE;
    #pragma unroll
    for (int n = 0; n < DSTATE; ++n) Hc[cbase + n] = h[n];
    Ds[(size_t)(b * NC + c) * DI + e] = dsum;
}

__global__ __launch_bounds__(256) void scan_compose(const float* __restrict__ Ds,
                                                    const float* __restrict__ A_log,
                                                    float* __restrict__ Hc) {
    const int id = blockIdx.x * 256 + threadIdx.x;   // b*DI*16 + e*16 + n
    const int b = id / (DI * DSTATE);
    const int r = id - b * (DI * DSTATE);
    const int e = r >> 4;
    const float aen = -expf(A_log[r]) * LOG2E;       // A_log[e*16+n] == A_log[r]
    float cur = 0.f;
    for (int c = 0; c < NC; ++c) {
        const size_t base = (size_t)(b * NC + c) * DI;
        float p  = exp2f(aen * Ds[base + e]);
        const size_t idx = base * DSTATE + r;
        float hl = Hc[idx];
        Hc[idx] = cur;              // h_in for chunk c
        cur = p * cur + hl;
    }
}

__global__ __launch_bounds__(256) void scan_apply(const float* __restrict__ delta,
                                                  const float* __restrict__ xa,
                                                  const float* __restrict__ dbc,
                                                  const float* __restrict__ xz,
                                                  const float* __restrict__ A_log,
                                                  const float* __restrict__ Dp,
                                                  const float* __restrict__ Hc,
                                                  ushort_t* __restrict__ ys) {
    const int e = blockIdx.x * 256 + threadIdx.x;
    const int c = blockIdx.y;
    const int b = blockIdx.z;
    float aen[DSTATE], h[DSTATE];
    const size_t cbase = ((size_t)(b * NC + c) * DI + e) * DSTATE;
    #pragma unroll
    for (int n = 0; n < DSTATE; ++n) {
        aen[n] = -expf(A_log[e * DSTATE + n]) * LOG2E;
        h[n] = Hc[cbase + n];
    }
    const float dpe = Dp[e];
    const int t0 = b * LL + c * CL;
    const float* dp = delta + (size_t)t0 * DI + e;
    const float* xp = xa    + (size_t)t0 * DI + e;
    const float* bp = dbc   + (size_t)t0 * NDBC + DTRANK;
    const float* zp = xz    + (size_t)t0 * DI2 + DI + e;
    ushort_t*    yp = ys    + (size_t)t0 * DI + e;
    for (int l = 0; l < CL; ++l) {
        float d  = dp[(size_t)l * DI];
        float xv = xp[(size_t)l * DI];
        const float* br = bp + (size_t)l * NDBC;       // B row (uniform)
        const float* cr = br + DSTATE;                 // C row (uniform)
        float dxv = d * xv;
        float y = 0.f;
        #pragma unroll
        for (int n = 0; n < DSTATE; ++n) {
            float dA = exp2f(d * aen[n]);
            h[n] = dA * h[n] + dxv * br[n];
            y += h[n] * cr[n];
        }
        float z = zp[(size_t)l * DI2];
        float sz = z / (1.f + expf(-z));
        yp[(size_t)l * DI] = f2bf((y + dpe * xv) * sz);
    }
}

// ------------------- host launcher -------------------
extern "C" void kernel_launch(void* const* d_in, const int* in_sizes, int n_in,
                              void* d_out, int out_size, void* d_ws, size_t ws_size,
                              hipStream_t stream) {
    const int*   x        = (const int*)  d_in[0];
    const float* embed_W  = (const float*)d_in[1];
    const float* norm_w   = (const float*)d_in[2];
    const float* in_w     = (const float*)d_in[3];   // (2, 3072, 768)
    const float* conv_w   = (const float*)d_in[4];
    const float* conv_b   = (const float*)d_in[5];
    const float* xproj_w  = (const float*)d_in[6];   // (2, 80, 1536)
    const float* dt_w     = (const float*)d_in[7];   // (2, 1536, 48)
    const float* dt_b     = (const float*)d_in[8];
    const float* A_log    = (const float*)d_in[9];
    const float* D_param  = (const float*)d_in[10];
    const float* out_w    = (const float*)d_in[11];  // (2, 768, 1536)
    const float* normf_w  = (const float*)d_in[12];
    const float* head_w   = (const float*)d_in[13];  // (32000, 768)
    const float* head_b   = (const float*)d_in[14];
    float* logits = (float*)d_out;

    // ---- workspace carve-up ----
    float* ws    = (float*)d_ws;
    float* h     = ws;                         // NT*DM
    float* xz    = h     + (size_t)NT * DM;    // NT*DI2
    float* xa    = xz    + (size_t)NT * DI2;   // NT*DI
    float* dbc   = xa    + (size_t)NT * DI;    // NT*NDBC
    float* delta = dbc   + (size_t)NT * NDBC;  // NT*DI
    ushort_t* in_wb  = (ushort_t*)(delta + (size_t)NT * DI);  // 2*DI2*DM
    ushort_t* out_wb = in_wb  + (size_t)2 * DI2 * DM;         // 2*DM*DI
    ushort_t* xnb    = out_wb + (size_t)2 * DM * DI;          // NT*DM
    ushort_t* ys16   = xnb    + (size_t)NT * DM;              // NT*DI
    float* Ds = (float*)(ys16 + (size_t)NT * DI);             // BB*NC*DI
    float* Hc = Ds + (size_t)BB * NC * DI;                    // BB*NC*DI*16
    // head_wb (32000*768 bf16 = 49.2 MB) aliases xz..delta (50.9 MB), dead at head time
    ushort_t* head_wb = (ushort_t*)xz;

    // 1. embedding
    embed_kernel<<<NT, 192, 0, stream>>>(x, embed_W, h);

    // 2. weight conversions (layer weights; head_w later, its buffer aliases xz)
    {
        int n4 = 2 * DI2 * DM / 4;
        f2b_kernel<<<(n4 + 255) / 256, 256, 0, stream>>>(in_w, in_wb, n4);
        n4 = 2 * DM * DI / 4;
        f2b_kernel<<<(n4 + 255) / 256, 256, 0, stream>>>(out_w, out_wb, n4);
    }

    for (int i = 0; i < 2; ++i) {
        // rmsnorm -> bf16 (+ zero xz for split-K in_proj)
        rmsnorm_kernel<<<NT, 256, 0, stream>>>(h, norm_w + (size_t)i * DM, xnb, xz);
        // in_proj: xz = xn @ in_w^T   (2048 x 3072, K=768) [MFMA, split-K x2]
        bgemm_bt<<<dim3(NT / 128, DI2 / 128, 2), 256, 0, stream>>>(
            xnb, DM, in_wb + (size_t)i * DI2 * DM, DM, xz, DI2, DM, nullptr, nullptr);
        // conv + silu (+ dbc zero-init for split-K x_proj)
        conv_silu_kernel<<<(NT * DI + 255) / 256, 256, 0, stream>>>(
            xz, conv_w + (size_t)i * DI * 4, conv_b + (size_t)i * DI, xa, dbc);
        // x_proj: dbc = xa @ xproj_w^T  (2048 x 80, K=1536) [fp32, split-K x8]
        sgemm_bt<<<dim3(NT / BM, (NDBC + BN - 1) / BN, 8), 256, 0, stream>>>(
            xa, DI, xproj_w + (size_t)i * NDBC * DI, DI, dbc, NDBC,
            NT, NDBC, DI, nullptr, nullptr, 0);
        // dt_proj + bias + softplus  (2048 x 1536, K=48) [fp32]
        sgemm_bt<<<dim3(NT / BM, DI / BN), 256, 0, stream>>>(
            dbc, NDBC, dt_w + (size_t)i * DI * DTRANK, DTRANK, delta, DI,
            NT, DI, DTRANK, dt_b + (size_t)i * DI, nullptr, 1);
        // chunked selective scan -> ys (bf16)
        scan_carry<<<dim3(DI / 256, NC, BB), 256, 0, stream>>>(
            delta, xa, dbc, A_log + (size_t)i * DI * DSTATE, Ds, Hc);
        scan_compose<<<(BB * DI * DSTATE) / 256, 256, 0, stream>>>(
            Ds, A_log + (size_t)i * DI * DSTATE, Hc);
        scan_apply<<<dim3(DI / 256, NC, BB), 256, 0, stream>>>(
            delta, xa, dbc, xz, A_log + (size_t)i * DI * DSTATE,
            D_param + (size_t)i * DI, Hc, ys16);
        // out_proj + residual: h += ys @ out_w^T  (2048 x 768, K=1536)
        // [MFMA, split-K x4; h already holds residual -> atomicAdd epilogue]
        bgemm_bt<<<dim3(NT / 128, DM / 128, 4), 256, 0, stream>>>(
            ys16, DI, out_wb + (size_t)i * DM * DI, DI, h, DM, DI, nullptr, nullptr);
    }

    // final rmsnorm -> bf16 (no zero-fill)
    rmsnorm_kernel<<<NT, 256, 0, stream>>>(h, normf_w, xnb, nullptr);
    // head weight conversion (xz region now dead)
    {
        int n4 = NVOCAB * DM / 4;
        f2b_kernel<<<(n4 + 255) / 256, 256, 0, stream>>>(head_w, head_wb, n4);
    }
    // head: logits = xn @ head_w^T + head_b  (2048 x 32000, K=768) [MFMA]
    bgemm_bt<<<dim3(NT / 128, NVOCAB / 128), 256, 0, stream>>>(
        xnb, DM, head_wb, DM, logits, NVOCAB, DM, head_b, nullptr);
}

// Round 7
// 848.915 us; speedup vs baseline: 1.1873x; 1.1873x over previous
//
#include <hip/hip_runtime.h>
#include <cmath>

// ---- problem constants ----
constexpr int DM     = 768;     // d_model
constexpr int DI     = 1536;    // d_inner
constexpr int DI2    = 3072;    // 2*d_inner
constexpr int DSTATE = 16;
constexpr int DTRANK = 48;
constexpr int NDBC   = 80;      // dt_rank + 2*d_state
constexpr int BB     = 2;
constexpr int LL     = 1024;
constexpr int NT     = BB * LL; // 2048 tokens
constexpr int NVOCAB = 32000;
constexpr float EPSF = 1e-5f;
constexpr float LOG2E = 1.4426950408889634f;

// chunked scan parameters
constexpr int NC = 64;          // chunks along L
constexpr int CL = LL / NC;     // 16 steps per chunk

// out_proj split-K slices (partial-buffer, no atomics)
constexpr int OPZ = 4;

typedef unsigned short ushort_t;
typedef __bf16 bf16x8 __attribute__((ext_vector_type(8)));
typedef float  f32x4  __attribute__((ext_vector_type(4)));

__device__ inline ushort_t f2bf(float x) {
    unsigned int u = __builtin_bit_cast(unsigned int, x);
    unsigned int r = (u + 0x7FFFu + ((u >> 16) & 1u)) >> 16;
    return (ushort_t)r;
}

// ------------------- fp32 -> bf16 bulk convert (RNE) -------------------
__global__ __launch_bounds__(256) void f2b_kernel(const float* __restrict__ in,
                                                  ushort_t* __restrict__ out, int n4) {
    int i = blockIdx.x * blockDim.x + threadIdx.x;
    if (i >= n4) return;
    float4 v = ((const float4*)in)[i];
    ushort4 o;
    o.x = f2bf(v.x); o.y = f2bf(v.y); o.z = f2bf(v.z); o.w = f2bf(v.w);
    ((ushort4*)out)[i] = o;
}

// ------------------- embedding gather -------------------
__global__ void embed_kernel(const int* __restrict__ x, const float* __restrict__ W,
                             float* __restrict__ h) {
    int t = blockIdx.x;
    int row = x[t];
    const float4* src = (const float4*)(W + (size_t)row * DM);
    float4* dst = (float4*)(h + (size_t)t * DM);
    for (int i = threadIdx.x; i < DM / 4; i += blockDim.x) dst[i] = src[i];
}

// ------------------- per-token RMSNorm, bf16 output -------------------
// If partials != null: h[t] += sum_{s<OPZ} partials[s][t] (out_proj split-K
// reduction fused here), h written back (residual stream), then normalized.
__global__ __launch_bounds__(256) void rmsnorm_kernel(float* __restrict__ x,
                                                      const float* __restrict__ w,
                                                      ushort_t* __restrict__ o,
                                                      const float* __restrict__ partials) {
    int t = blockIdx.x;
    float* xr = x + (size_t)t * DM;
    float hv[3];                         // DM/256 = 3 elems per thread
    float s = 0.f;
    #pragma unroll
    for (int i = 0; i < 3; ++i) {
        const int idx = threadIdx.x + i * 256;
        float v = xr[idx];
        if (partials) {
            #pragma unroll
            for (int ss = 0; ss < OPZ; ++ss)
                v += partials[(size_t)ss * NT * DM + (size_t)t * DM + idx];
            xr[idx] = v;                 // write back updated residual
        }
        hv[i] = v;
        s += v * v;
    }
    #pragma unroll
    for (int off = 32; off >= 1; off >>= 1) s += __shfl_down(s, off, 64);
    __shared__ float wsum[4];
    if ((threadIdx.x & 63) == 0) wsum[threadIdx.x >> 6] = s;
    __syncthreads();
    float tot = wsum[0] + wsum[1] + wsum[2] + wsum[3];
    float r = rsqrtf(tot / DM + EPSF);
    ushort_t* orow = o + (size_t)t * DM;
    #pragma unroll
    for (int i = 0; i < 3; ++i) {
        const int idx = threadIdx.x + i * 256;
        orow[idx] = f2bf(hv[i] * r * w[idx]);
    }
}

// ------------------- bf16 MFMA GEMM: C[m,n] = sum_k A[m,k]*W[n,k] -------------------
// EXACT r4 structure (head ran 165 us, VGPR 76): 128x128 tile, BK=32, 4 waves,
// T1 XCD swizzle + T2 both-sides XOR swizzle + depth-2 counted pipeline @32KB
// + T5 setprio. NO split-K branch here (r6 showed the branch alone perturbs
// codegen and costs the head ~28 us).
__device__ inline void gl_lds16(const void* g, void* l) {
    auto gp = (const __attribute__((address_space(1))) void*)(unsigned long long)(uintptr_t)g;
    auto lp = (__attribute__((address_space(3))) void*)(unsigned int)(uintptr_t)l;
    __builtin_amdgcn_global_load_lds(gp, lp, 16, 0, 0);
}

__global__ __launch_bounds__(256) void bgemm_bt(const ushort_t* __restrict__ A, int lda,
                                                const ushort_t* __restrict__ W, int ldw,
                                                float* __restrict__ C, int ldc,
                                                int K,
                                                const float* __restrict__ bias,
                                                const float* __restrict__ resid) {
    __shared__ ushort_t As[2][128 * 32];
    __shared__ ushort_t Bs[2][128 * 32];

    // T1: bijective XCD swizzle (m204): contiguous wg chunks per XCD
    const int GX  = gridDim.x;
    const int nwg = GX * gridDim.y;
    int orig = blockIdx.y * GX + blockIdx.x;
    int q = nwg >> 3, r = nwg & 7, xcd = orig & 7, lq = orig >> 3;
    int wg = (xcd < r ? xcd * (q + 1) : r * (q + 1) + (xcd - r) * q) + lq;
    const int m0 = (wg % GX) * 128;
    const int n0 = (wg / GX) * 128;

    const int wave = threadIdx.x >> 6;
    const int lane = threadIdx.x & 63;
    const int lrow = lane >> 2;          // 0..15 (staging row within 16-row group)

    f32x4 acc[4][4] = {};

    const ushort_t* Ab = A + (size_t)m0 * lda;
    const ushort_t* Wb = W + (size_t)n0 * ldw;
    const int wm = (wave >> 1) * 64;
    const int wn = (wave & 1) * 64;

    auto stage = [&](int buf, int k0) {
        #pragma unroll
        for (int rr = 0; rr < 2; ++rr) {
            const int rowbase = rr * 64 + wave * 16;
            const int row = rowbase + lrow;
            const int csw = (((lane & 3) ^ ((row >> 1) & 3)) << 3);   // elems
            gl_lds16(Ab + (size_t)row * lda + k0 + csw, (char*)As[buf] + rowbase * 64);
            gl_lds16(Wb + (size_t)row * ldw + k0 + csw, (char*)Bs[buf] + rowbase * 64);
        }
    };

    const int S = K >> 5;                // K-steps (>=2 for all our shapes)
    stage(0, 0);
    stage(1, 32);

    const int rsw = ((lane >> 1) & 3);   // swz(row) for read: row&15 == lane&15
    for (int s = 0; s < S; ++s) {
        if (s < S - 1) asm volatile("s_waitcnt vmcnt(4)" ::: "memory");
        else           asm volatile("s_waitcnt vmcnt(0)" ::: "memory");
        __builtin_amdgcn_s_barrier();            // (A) publish buf[s&1]

        const int cur = s & 1;
        bf16x8 af[4], bfr[4];
        const int rchunk = (((lane >> 4) ^ rsw) << 4);   // bytes
        #pragma unroll
        for (int i = 0; i < 4; ++i) {
            af[i]  = *(const bf16x8*)((char*)As[cur] + (wm + i * 16 + (lane & 15)) * 64 + rchunk);
            bfr[i] = *(const bf16x8*)((char*)Bs[cur] + (wn + i * 16 + (lane & 15)) * 64 + rchunk);
        }
        asm volatile("s_waitcnt lgkmcnt(0)" ::: "memory");  // my reads in regs
        __builtin_amdgcn_sched_barrier(0);
        __builtin_amdgcn_s_barrier();            // (B) all waves' reads of buf[cur] done
        if (s + 2 < S) stage(cur, (s + 2) << 5); // overwrite buf[cur] with tile s+2

        __builtin_amdgcn_s_setprio(1);
        #pragma unroll
        for (int i = 0; i < 4; ++i)
            #pragma unroll
            for (int j = 0; j < 4; ++j)
                acc[i][j] = __builtin_amdgcn_mfma_f32_16x16x32_bf16(af[i], bfr[j], acc[i][j], 0, 0, 0);
        __builtin_amdgcn_s_setprio(0);
    }

    // epilogue: C/D layout col=lane&15, row=(lane>>4)*4+reg
    const int cn = lane & 15;
    const int cr = (lane >> 4) * 4;
    #pragma unroll
    for (int i = 0; i < 4; ++i) {
        #pragma unroll
        for (int j = 0; j < 4; ++j) {
            const int col = n0 + wn + j * 16 + cn;
            const float bv = bias ? bias[col] : 0.f;
            #pragma unroll
            for (int rr = 0; rr < 4; ++rr) {
                const int row = m0 + wm + i * 16 + cr + rr;
                const size_t idx = (size_t)row * ldc + col;
                float v = acc[i][j][rr] + bv;
                if (resid) v += resid[idx];
                C[idx] = v;
            }
        }
    }
}

// Split-K clone: gridDim.z slices of K, each writes a PARTIAL result with
// plain stores to C + z*M*ldc (no atomics, no zero-fill). Reduction is fused
// into the consumer (rmsnorm). Separate kernel so bgemm_bt codegen is untouched.
__global__ __launch_bounds__(256) void bgemm_bt_sk(const ushort_t* __restrict__ A, int lda,
                                                   const ushort_t* __restrict__ W, int ldw,
                                                   float* __restrict__ C, int ldc,
                                                   int K) {
    __shared__ ushort_t As[2][128 * 32];
    __shared__ ushort_t Bs[2][128 * 32];

    const int GX  = gridDim.x;
    const int nwg = GX * gridDim.y;
    int orig = blockIdx.y * GX + blockIdx.x;
    int q = nwg >> 3, r = nwg & 7, xcd = orig & 7, lq = orig >> 3;
    int wg = (xcd < r ? xcd * (q + 1) : r * (q + 1) + (xcd - r) * q) + lq;
    const int m0 = (wg % GX) * 128;
    const int n0 = (wg / GX) * 128;

    const int Kc   = K / gridDim.z;
    const int kbeg = blockIdx.z * Kc;
    float* Cz = C + (size_t)blockIdx.z * (size_t)GX * 128 * ldc;

    const int wave = threadIdx.x >> 6;
    const int lane = threadIdx.x & 63;
    const int lrow = lane >> 2;

    f32x4 acc[4][4] = {};

    const ushort_t* Ab = A + (size_t)m0 * lda + kbeg;
    const ushort_t* Wb = W + (size_t)n0 * ldw + kbeg;
    const int wm = (wave >> 1) * 64;
    const int wn = (wave & 1) * 64;

    auto stage = [&](int buf, int k0) {
        #pragma unroll
        for (int rr = 0; rr < 2; ++rr) {
            const int rowbase = rr * 64 + wave * 16;
            const int row = rowbase + lrow;
            const int csw = (((lane & 3) ^ ((row >> 1) & 3)) << 3);
            gl_lds16(Ab + (size_t)row * lda + k0 + csw, (char*)As[buf] + rowbase * 64);
            gl_lds16(Wb + (size_t)row * ldw + k0 + csw, (char*)Bs[buf] + rowbase * 64);
        }
    };

    const int S = Kc >> 5;               // requires Kc%32==0, S>=2
    stage(0, 0);
    stage(1, 32);

    const int rsw = ((lane >> 1) & 3);
    for (int s = 0; s < S; ++s) {
        if (s < S - 1) asm volatile("s_waitcnt vmcnt(4)" ::: "memory");
        else           asm volatile("s_waitcnt vmcnt(0)" ::: "memory");
        __builtin_amdgcn_s_barrier();

        const int cur = s & 1;
        bf16x8 af[4], bfr[4];
        const int rchunk = (((lane >> 4) ^ rsw) << 4);
        #pragma unroll
        for (int i = 0; i < 4; ++i) {
            af[i]  = *(const bf16x8*)((char*)As[cur] + (wm + i * 16 + (lane & 15)) * 64 + rchunk);
            bfr[i] = *(const bf16x8*)((char*)Bs[cur] + (wn + i * 16 + (lane & 15)) * 64 + rchunk);
        }
        asm volatile("s_waitcnt lgkmcnt(0)" ::: "memory");
        __builtin_amdgcn_sched_barrier(0);
        __builtin_amdgcn_s_barrier();
        if (s + 2 < S) stage(cur, (s + 2) << 5);

        __builtin_amdgcn_s_setprio(1);
        #pragma unroll
        for (int i = 0; i < 4; ++i)
            #pragma unroll
            for (int j = 0; j < 4; ++j)
                acc[i][j] = __builtin_amdgcn_mfma_f32_16x16x32_bf16(af[i], bfr[j], acc[i][j], 0, 0, 0);
        __builtin_amdgcn_s_setprio(0);
    }

    const int cn = lane & 15;
    const int cr = (lane >> 4) * 4;
    #pragma unroll
    for (int i = 0; i < 4; ++i)
        #pragma unroll
        for (int j = 0; j < 4; ++j) {
            const int col = n0 + wn + j * 16 + cn;
            #pragma unroll
            for (int rr = 0; rr < 4; ++rr) {
                const int row = m0 + wm + i * 16 + cr + rr;
                Cz[(size_t)row * ldc + col] = acc[i][j][rr];
            }
        }
}

// ------------------- fp32 tiled GEMM (small N / small K cases) -------------------
// gridDim.z > 1 => split-K: each z-slice handles K/gridDim.z, accumulates into C
// via atomicAdd (C must be pre-zeroed; bias/resid/act must be off on that path).
constexpr int BM = 64, BN = 64, BK = 16;
__global__ __launch_bounds__(256) void sgemm_bt(const float* __restrict__ A, int lda,
                                                const float* __restrict__ W, int ldw,
                                                float* __restrict__ C, int ldc,
                                                int M, int N, int K,
                                                const float* __restrict__ bias,
                                                const float* __restrict__ resid,
                                                int act) {
    __shared__ float As[BK][BM];
    __shared__ float Ws[BK][BN];
    const int m0 = blockIdx.x * BM;
    const int n0 = blockIdx.y * BN;
    const int nz = gridDim.z;
    const int Kc = K / nz;
    const int kbeg = blockIdx.z * Kc;
    const int kend = kbeg + Kc;
    const int tid = threadIdx.x;
    const int tn = tid & 15, tm = tid >> 4;
    const int lr = tid >> 2;
    const int lk = (tid & 3) * 4;

    float acc[4][4] = {};

    for (int k0 = kbeg; k0 < kend; k0 += BK) {
        {
            float4 v = *(const float4*)(A + (size_t)(m0 + lr) * lda + k0 + lk);
            As[lk + 0][lr] = v.x; As[lk + 1][lr] = v.y;
            As[lk + 2][lr] = v.z; As[lk + 3][lr] = v.w;
            int n = n0 + lr;
            float4 u = make_float4(0.f, 0.f, 0.f, 0.f);
            if (n < N) u = *(const float4*)(W + (size_t)n * ldw + k0 + lk);
            Ws[lk + 0][lr] = u.x; Ws[lk + 1][lr] = u.y;
            Ws[lk + 2][lr] = u.z; Ws[lk + 3][lr] = u.w;
        }
        __syncthreads();
        #pragma unroll
        for (int kk = 0; kk < BK; ++kk) {
            float4 a = *(const float4*)&As[kk][tm * 4];
            float4 w = *(const float4*)&Ws[kk][tn * 4];
            acc[0][0] += a.x * w.x; acc[0][1] += a.x * w.y; acc[0][2] += a.x * w.z; acc[0][3] += a.x * w.w;
            acc[1][0] += a.y * w.x; acc[1][1] += a.y * w.y; acc[1][2] += a.y * w.z; acc[1][3] += a.y * w.w;
            acc[2][0] += a.z * w.x; acc[2][1] += a.z * w.y; acc[2][2] += a.z * w.z; acc[2][3] += a.z * w.w;
            acc[3][0] += a.w * w.x; acc[3][1] += a.w * w.y; acc[3][2] += a.w * w.z; acc[3][3] += a.w * w.w;
        }
        __syncthreads();
    }

    #pragma unroll
    for (int i = 0; i < 4; ++i) {
        int m = m0 + tm * 4 + i;
        #pragma unroll
        for (int j = 0; j < 4; ++j) {
            int n = n0 + tn * 4 + j;
            if (n < N) {
                const size_t idx = (size_t)m * ldc + n;
                float v = acc[i][j];
                if (nz > 1) {
                    atomicAdd(&C[idx], v);
                } else {
                    if (bias)  v += bias[n];
                    if (resid) v += resid[idx];
                    if (act == 1) v = (v > 20.f) ? v : log1pf(expf(v));
                    C[idx] = v;
                }
            }
        }
    }
}

// ------------------- causal depthwise conv (k=4) + bias + silu -------------------
// also zero-fills dbc (split-K x_proj accumulates into it afterwards)
__global__ void conv_silu_kernel(const float* __restrict__ xz, const float* __restrict__ cw,
                                 const float* __restrict__ cb, float* __restrict__ xa,
                                 float* __restrict__ dbc0) {
    int idx = blockIdx.x * blockDim.x + threadIdx.x;
    if (idx < NT * NDBC) dbc0[idx] = 0.f;
    if (idx >= NT * DI) return;
    int e = idx % DI;
    int t = idx / DI;
    int l = t & (LL - 1);
    float acc = cb[e];
    #pragma unroll
    for (int k = 0; k < 4; ++k) {
        int ll = l - 3 + k;
        if (ll >= 0) acc += cw[e * 4 + k] * xz[(size_t)(t - 3 + k) * DI2 + e];
    }
    xa[idx] = acc / (1.f + expf(-acc));   // silu
}

// ------------------- chunked selective scan -------------------
// h_t = dA_t*h_{t-1} + dBx_t (linear) -> per-chunk carry/compose/apply.
// exp-chain fast path: with A_log = log(arange(1..16)) (this model's data),
// aen[n] = (n+1)*aen[0], so dA_n = exp2(d*aen[n]) = t^(n+1) with
// t = exp2(d*aen[0]): 16 transcendentals -> 1 + 15 muls per step.
// Runtime pattern check (uniform branch) falls back to exact exp2 otherwise.

__global__ __launch_bounds__(256) void scan_carry(const float* __restrict__ delta,
                                                  const float* __restrict__ xa,
                                                  const float* __restrict__ dbc,
                                                  const float* __restrict__ A_log,
                                                  float* __restrict__ Ds,
                                                  float* __restrict__ Hc) {
    const int e = blockIdx.x * 256 + threadIdx.x;
    const int c = blockIdx.y;
    const int b = blockIdx.z;
    float aen[DSTATE], h[DSTATE];
    #pragma unroll
    for (int n = 0; n < DSTATE; ++n) {
        aen[n] = -expf(A_log[e * DSTATE + n]) * LOG2E;
        h[n] = 0.f;
    }
    const float aen0 = aen[0];
    bool fast = true;
    #pragma unroll
    for (int n = 1; n < DSTATE; ++n)
        fast = fast && (fabsf(aen[n] - (float)(n + 1) * aen0) <= 1e-4f * (float)(n + 1) * fabsf(aen0));

    float dsum = 0.f;
    const int t0 = b * LL + c * CL;
    const float* dp = delta + (size_t)t0 * DI + e;
    const float* xp = xa    + (size_t)t0 * DI + e;
    const float* bp = dbc   + (size_t)t0 * NDBC + DTRANK;
    if (fast) {
        for (int l = 0; l < CL; ++l) {
            float d  = dp[(size_t)l * DI];
            float xv = xp[(size_t)l * DI];
            const float* br = bp + (size_t)l * NDBC;
            dsum += d;
            float dxv = d * xv;
            float t = exp2f(d * aen0);
            float p = 1.f;
            #pragma unroll
            for (int n = 0; n < DSTATE; ++n) {
                p *= t;                              // p = t^(n+1) = dA_n
                h[n] = p * h[n] + dxv * br[n];
            }
        }
    } else {
        for (int l = 0; l < CL; ++l) {
            float d  = dp[(size_t)l * DI];
            float xv = xp[(size_t)l * DI];
            const float* br = bp + (size_t)l * NDBC;
            dsum += d;
            float dxv = d * xv;
            #pragma unroll
            for (int n = 0; n < DSTATE; ++n) {
                float dA = exp2f(d * aen[n]);
                h[n] = dA * h[n] + dxv * br[n];
            }
        }
    }
    const size_t cbase = ((size_t)(b * NC + c) * DI + e) * DSTATE;
    #pragma unroll
    for (int n = 0; n < DSTATE; ++n) Hc[cbase + n] = h[n];
    Ds[(size_t)(b * NC + c) * DI + e] = dsum;
}

__global__ __launch_bounds__(256) void scan_compose(const float* __restrict__ Ds,
                                                    const float* __restrict__ A_log,
                                                    float* __restrict__ Hc) {
    const int id = blockIdx.x * 256 + threadIdx.x;   // b*DI*16 + e*16 + n
    const int b = id / (DI * DSTATE);
    const int r = id - b * (DI * DSTATE);
    const int e = r >> 4;
    const float aen = -expf(A_log[r]) * LOG2E;
    float cur = 0.f;
    for (int c = 0; c < NC; ++c) {
        const size_t base = (size_t)(b * NC + c) * DI;
        float p  = exp2f(aen * Ds[base + e]);
        const size_t idx = base * DSTATE + r;
        float hl = Hc[idx];
        Hc[idx] = cur;              // h_in for chunk c
        cur = p * cur + hl;
    }
}

__global__ __launch_bounds__(256) void scan_apply(const float* __restrict__ delta,
                                                  const float* __restrict__ xa,
                                                  const float* __restrict__ dbc,
                                                  const float* __restrict__ xz,
                                                  const float* __restrict__ A_log,
                                                  const float* __restrict__ Dp,
                                                  const float* __restrict__ Hc,
                                                  ushort_t* __restrict__ ys) {
    const int e = blockIdx.x * 256 + threadIdx.x;
    const int c = blockIdx.y;
    const int b = blockIdx.z;
    float aen[DSTATE], h[DSTATE];
    const size_t cbase = ((size_t)(b * NC + c) * DI + e) * DSTATE;
    #pragma unroll
    for (int n = 0; n < DSTATE; ++n) {
        aen[n] = -expf(A_log[e * DSTATE + n]) * LOG2E;
        h[n] = Hc[cbase + n];
    }
    const float aen0 = aen[0];
    bool fast = true;
    #pragma unroll
    for (int n = 1; n < DSTATE; ++n)
        fast = fast && (fabsf(aen[n] - (float)(n + 1) * aen0) <= 1e-4f * (float)(n + 1) * fabsf(aen0));

    const float dpe = Dp[e];
    const int t0 = b * LL + c * CL;
    const float* dp = delta + (size_t)t0 * DI + e;
    const float* xp = xa    + (size_t)t0 * DI + e;
    const float* bp = dbc   + (size_t)t0 * NDBC + DTRANK;
    const float* zp = xz    + (size_t)t0 * DI2 + DI + e;
    ushort_t*    yp = ys    + (size_t)t0 * DI + e;
    if (fast) {
        for (int l = 0; l < CL; ++l) {
            float d  = dp[(size_t)l * DI];
            float xv = xp[(size_t)l * DI];
            const float* br = bp + (size_t)l * NDBC;   // B row (uniform)
            const float* cr = br + DSTATE;             // C row (uniform)
            float dxv = d * xv;
            float y = 0.f;
            float t = exp2f(d * aen0);
            float p = 1.f;
            #pragma unroll
            for (int n = 0; n < DSTATE; ++n) {
                p *= t;
                h[n] = p * h[n] + dxv * br[n];
                y += h[n] * cr[n];
            }
            float z = zp[(size_t)l * DI2];
            float sz = z / (1.f + expf(-z));
            yp[(size_t)l * DI] = f2bf((y + dpe * xv) * sz);
        }
    } else {
        for (int l = 0; l < CL; ++l) {
            float d  = dp[(size_t)l * DI];
            float xv = xp[(size_t)l * DI];
            const float* br = bp + (size_t)l * NDBC;
            const float* cr = br + DSTATE;
            float dxv = d * xv;
            float y = 0.f;
            #pragma unroll
            for (int n = 0; n < DSTATE; ++n) {
                float dA = exp2f(d * aen[n]);
                h[n] = dA * h[n] + dxv * br[n];
                y += h[n] * cr[n];
            }
            float z = zp[(size_t)l * DI2];
            float sz = z / (1.f + expf(-z));
            yp[(size_t)l * DI] = f2bf((y + dpe * xv) * sz);
        }
    }
}

// ------------------- host launcher -------------------
extern "C" void kernel_launch(void* const* d_in, const int* in_sizes, int n_in,
                              void* d_out, int out_size, void* d_ws, size_t ws_size,
                              hipStream_t stream) {
    const int*   x        = (const int*)  d_in[0];
    const float* embed_W  = (const float*)d_in[1];
    const float* norm_w   = (const float*)d_in[2];
    const float* in_w     = (const float*)d_in[3];   // (2, 3072, 768)
    const float* conv_w   = (const float*)d_in[4];
    const float* conv_b   = (const float*)d_in[5];
    const float* xproj_w  = (const float*)d_in[6];   // (2, 80, 1536)
    const float* dt_w     = (const float*)d_in[7];   // (2, 1536, 48)
    const float* dt_b     = (const float*)d_in[8];
    const float* A_log    = (const float*)d_in[9];
    const float* D_param  = (const float*)d_in[10];
    const float* out_w    = (const float*)d_in[11];  // (2, 768, 1536)
    const float* normf_w  = (const float*)d_in[12];
    const float* head_w   = (const float*)d_in[13];  // (32000, 768)
    const float* head_b   = (const float*)d_in[14];
    float* logits = (float*)d_out;

    // ---- workspace carve-up ----
    float* ws    = (float*)d_ws;
    float* h     = ws;                         // NT*DM
    float* xz    = h     + (size_t)NT * DM;    // NT*DI2
    float* xa    = xz    + (size_t)NT * DI2;   // NT*DI
    float* dbc   = xa    + (size_t)NT * DI;    // NT*NDBC
    float* delta = dbc   + (size_t)NT * NDBC;  // NT*DI
    ushort_t* in_wb  = (ushort_t*)(delta + (size_t)NT * DI);  // 2*DI2*DM
    ushort_t* out_wb = in_wb  + (size_t)2 * DI2 * DM;         // 2*DM*DI
    ushort_t* xnb    = out_wb + (size_t)2 * DM * DI;          // NT*DM
    ushort_t* ys16   = xnb    + (size_t)NT * DM;              // NT*DI
    float* Ds   = (float*)(ys16 + (size_t)NT * DI);           // BB*NC*DI
    float* Hc   = Ds + (size_t)BB * NC * DI;                  // BB*NC*DI*16
    float* Pout = Hc + (size_t)BB * NC * DI * DSTATE;         // OPZ*NT*DM (25 MB)
    // head_wb (32000*768 bf16 = 49.2 MB) aliases xz..delta (50.9 MB), dead at head time
    ushort_t* head_wb = (ushort_t*)xz;

    // 1. embedding
    embed_kernel<<<NT, 192, 0, stream>>>(x, embed_W, h);

    // 2. weight conversions (layer weights; head_w later, its buffer aliases xz)
    {
        int n4 = 2 * DI2 * DM / 4;
        f2b_kernel<<<(n4 + 255) / 256, 256, 0, stream>>>(in_w, in_wb, n4);
        n4 = 2 * DM * DI / 4;
        f2b_kernel<<<(n4 + 255) / 256, 256, 0, stream>>>(out_w, out_wb, n4);
    }

    for (int i = 0; i < 2; ++i) {
        // rmsnorm -> bf16; for i==1 also reduces layer-0 out_proj partials into h
        rmsnorm_kernel<<<NT, 256, 0, stream>>>(
            h, norm_w + (size_t)i * DM, xnb, i == 0 ? nullptr : Pout);
        // in_proj: xz = xn @ in_w^T   (2048 x 3072, K=768) [MFMA]
        bgemm_bt<<<dim3(NT / 128, DI2 / 128), 256, 0, stream>>>(
            xnb, DM, in_wb + (size_t)i * DI2 * DM, DM, xz, DI2, DM, nullptr, nullptr);
        // conv + silu (+ dbc zero-init for split-K x_proj)
        conv_silu_kernel<<<(NT * DI + 255) / 256, 256, 0, stream>>>(
            xz, conv_w + (size_t)i * DI * 4, conv_b + (size_t)i * DI, xa, dbc);
        // x_proj: dbc = xa @ xproj_w^T  (2048 x 80, K=1536) [fp32, split-K x8]
        sgemm_bt<<<dim3(NT / BM, (NDBC + BN - 1) / BN, 8), 256, 0, stream>>>(
            xa, DI, xproj_w + (size_t)i * NDBC * DI, DI, dbc, NDBC,
            NT, NDBC, DI, nullptr, nullptr, 0);
        // dt_proj + bias + softplus  (2048 x 1536, K=48) [fp32]
        sgemm_bt<<<dim3(NT / BM, DI / BN), 256, 0, stream>>>(
            dbc, NDBC, dt_w + (size_t)i * DI * DTRANK, DTRANK, delta, DI,
            NT, DI, DTRANK, dt_b + (size_t)i * DI, nullptr, 1);
        // chunked selective scan -> ys (bf16)
        scan_carry<<<dim3(DI / 256, NC, BB), 256, 0, stream>>>(
            delta, xa, dbc, A_log + (size_t)i * DI * DSTATE, Ds, Hc);
        scan_compose<<<(BB * DI * DSTATE) / 256, 256, 0, stream>>>(
            Ds, A_log + (size_t)i * DI * DSTATE, Hc);
        scan_apply<<<dim3(DI / 256, NC, BB), 256, 0, stream>>>(
            delta, xa, dbc, xz, A_log + (size_t)i * DI * DSTATE,
            D_param + (size_t)i * DI, Hc, ys16);
        // out_proj: Pout[s] = ys @ out_w^T slice  (2048 x 768, K=1536/OPZ each)
        // [MFMA split-K, partial stores; reduction fused into next rmsnorm]
        bgemm_bt_sk<<<dim3(NT / 128, DM / 128, OPZ), 256, 0, stream>>>(
            ys16, DI, out_wb + (size_t)i * DM * DI, DI, Pout, DM, DI);
    }

    // final rmsnorm -> bf16 (reduces layer-1 out_proj partials into h)
    rmsnorm_kernel<<<NT, 256, 0, stream>>>(h, normf_w, xnb, Pout);
    // head weight conversion (xz region now dead)
    {
        int n4 = NVOCAB * DM / 4;
        f2b_kernel<<<(n4 + 255) / 256, 256, 0, stream>>>(head_w, head_wb, n4);
    }
    // head: logits = xn @ head_w^T + head_b  (2048 x 32000, K=768) [MFMA]
    bgemm_bt<<<dim3(NT / 128, NVOCAB / 128), 256, 0, stream>>>(
        xnb, DM, head_wb, DM, logits, NVOCAB, DM, head_b, nullptr);
}